// Round 3
// baseline (287.393 us; speedup 1.0000x reference)
//
#include <hip/hip_runtime.h>

// RBFolution: out[b,y,x,f] = exp(-beta[f] * (||patch||^2 - 2 patch.ccs[:,f] + ||ccs[:,f]||^2))
// x: [32,112,112,32] f32, ccs: [288,128] f32, beta: [128] f32, out: [32,110,110,128] f32
//
// bf16 MFMA implicit GEMM; p_sq/c_sq fp32-exact (only cross term bf16, err ~1e-5).
// R2: 2 output rows/block (x fetch 3x->2x), swapped MFMA operands so D=[filter][pixel]
// -> float4 output stores (14 dwordx4/thread vs 56 scalar).

typedef __attribute__((ext_vector_type(8))) short bf16x8;
typedef __attribute__((ext_vector_type(4))) float f32x4;

#define HH 112
#define WW 112
#define CC 32
#define HO 110
#define WO 110
#define NF 128
#define KD 288
#define RPX 114        // pixels per staged row in LDS (need up to px 113)
#define XP 40          // bf16 elems per pixel (32 + 8 pad) = 80 B = 5 x 16B-groups (odd -> conflict-free b128)

__device__ __forceinline__ unsigned short f32_to_bf16(float f) {
    unsigned u = __float_as_uint(f);
    unsigned r = u + 0x7FFFu + ((u >> 16) & 1u);   // round-to-nearest-even
    return (unsigned short)(r >> 16);
}

// --- Prologue: ccs [288][128] f32 -> ccs_t [128][288] bf16 ; c_sq[f] = sum_d ccs[d][f]^2 (f32)
__global__ __launch_bounds__(256) void rbf_prologue(const float* __restrict__ ccs,
                                                    unsigned short* __restrict__ ccs_t,
                                                    float* __restrict__ c_sq) {
    int idx = blockIdx.x * 256 + threadIdx.x;     // 0..36863, coalesced read
    int d = idx >> 7;
    int f = idx & 127;
    float v = ccs[idx];
    ccs_t[f * KD + d] = f32_to_bf16(v);
    atomicAdd(&c_sq[f], v * v);
}

// --- Main: one block per (y-pair, b). 2 output rows, 4 staged input rows.
__global__ __launch_bounds__(256) void rbf_main(const float* __restrict__ x,
                                                const unsigned short* __restrict__ ccs_t,
                                                const float* __restrict__ c_sq,
                                                const float* __restrict__ beta,
                                                float* __restrict__ out) {
    __shared__ unsigned short xs[4 * RPX * XP];    // 36480 B
    __shared__ float colsum[456];                   // 4 rows x 112 cols (stride 112) + overrun pad
    __shared__ float p_sq[2 * 112];

    const int t = threadIdx.x;
    const int y0 = blockIdx.x * 2;  // 0..108
    const int b = blockIdx.y;       // 0..31

    const float* xbase = x + (size_t)((b * HH + y0) * WW) * CC;

    // Stage x[y0..y0+3][0..111][0..31] -> LDS bf16; colsum from fp32 (exact p_sq).
    // 3584 float4 units = 14 * 256 exactly (no tail).
    #pragma unroll
    for (int p = 0; p < 14; ++p) {
        int idx = t + p * 256;
        int q = idx & 7;              // channel quarter (4 floats)
        int ic = idx >> 3;            // 0..447 = i*112 + col
        int col = ic % 112;
        int i = ic / 112;
        const float4 v = *(const float4*)(xbase + (i * WW + col) * CC + q * 4);
        unsigned short h0 = f32_to_bf16(v.x), h1 = f32_to_bf16(v.y);
        unsigned short h2 = f32_to_bf16(v.z), h3 = f32_to_bf16(v.w);
        uint2 pk;
        pk.x = (unsigned)h0 | ((unsigned)h1 << 16);
        pk.y = (unsigned)h2 | ((unsigned)h3 << 16);
        *(uint2*)(&xs[(i * RPX + col) * XP + q * 4]) = pk;
        float part = v.x * v.x + v.y * v.y + v.z * v.z + v.w * v.w;
        part += __shfl_xor(part, 1);
        part += __shfl_xor(part, 2);
        part += __shfl_xor(part, 4);
        if (q == 0) colsum[ic] = part;   // stride 112
    }
    __syncthreads();

    if (t < 224) {
        int r = (t >= 112) ? 1 : 0;
        int c = t - r * 112;
        float s = 0.f;
        #pragma unroll
        for (int i = 0; i < 3; ++i)
            #pragma unroll
            for (int j = 0; j < 3; ++j)
                s += colsum[(r + i) * 112 + c + j];   // c>=110 reads in-bounds garbage -> masked outputs only
        p_sq[t] = s;
    }
    __syncthreads();

    const int lane  = t & 63;
    const int wave  = t >> 6;            // 4 waves x 32 filters
    const int laneM = lane & 15;
    const int quad  = lane >> 4;

    // A = ccs (M = filters): lane's filter-in-tile = laneM
    const unsigned short* ap0 = ccs_t + (size_t)(wave * 32 + laneM) * KD + quad * 8;
    const unsigned short* ap1 = ap0 + 16 * KD;

    // per-lane 4 consecutive filters (rows of D): f = wave*32 + ft*16 + quad*4 + r
    const int fb = wave * 32 + quad * 4;
    const float4 cs0 = *(const float4*)(c_sq + fb);
    const float4 cs1 = *(const float4*)(c_sq + fb + 16);
    const float4 bt0 = *(const float4*)(beta + fb);
    const float4 bt1 = *(const float4*)(beta + fb + 16);

    #pragma unroll
    for (int r = 0; r < 2; ++r) {
        f32x4 acc[7][2];
        #pragma unroll
        for (int mi = 0; mi < 7; ++mi) {
            acc[mi][0] = (f32x4){0.f, 0.f, 0.f, 0.f};
            acc[mi][1] = (f32x4){0.f, 0.f, 0.f, 0.f};
        }

        #pragma unroll
        for (int kb = 0; kb < 9; ++kb) {     // one k-block per tap (ki,kj), K=32 channels
            const int ki = kb / 3, kj = kb % 3;
            bf16x8 a0 = *(const bf16x8*)(ap0 + kb * 32);
            bf16x8 a1 = *(const bf16x8*)(ap1 + kb * 32);
            #pragma unroll
            for (int mi = 0; mi < 7; ++mi) {
                // B[k = quad*8+j][n = laneM]: pixel px = mi*16+laneM, tap offset kj, staged row r+ki
                const bf16x8 bf = *(const bf16x8*)(&xs[((r + ki) * RPX + mi * 16 + laneM + kj) * XP + quad * 8]);
                acc[mi][0] = __builtin_amdgcn_mfma_f32_16x16x32_bf16(a0, bf, acc[mi][0], 0, 0, 0);
                acc[mi][1] = __builtin_amdgcn_mfma_f32_16x16x32_bf16(a1, bf, acc[mi][1], 0, 0, 0);
            }
        }

        // Epilogue: D[row = filter (quad*4+e)][col = pixel (laneM)] -> float4 stores along filters
        float* orow = out + (size_t)((b * HO + y0 + r) * WO) * NF;
        #pragma unroll
        for (int mi = 0; mi < 7; ++mi) {
            const int px = mi * 16 + laneM;
            const float ps = p_sq[r * 112 + px];
            float* op = orow + (size_t)px * NF + fb;
            #pragma unroll
            for (int ft = 0; ft < 2; ++ft) {
                const float4 cs = ft ? cs1 : cs0;
                const float4 bt = ft ? bt1 : bt0;
                float4 o;
                o.x = __expf(-bt.x * (ps - 2.f * acc[mi][ft][0] + cs.x));
                o.y = __expf(-bt.y * (ps - 2.f * acc[mi][ft][1] + cs.y));
                o.z = __expf(-bt.z * (ps - 2.f * acc[mi][ft][2] + cs.z));
                o.w = __expf(-bt.w * (ps - 2.f * acc[mi][ft][3] + cs.w));
                if (px < WO)
                    *(float4*)(op + ft * 16) = o;
            }
        }
    }
}

extern "C" void kernel_launch(void* const* d_in, const int* in_sizes, int n_in,
                              void* d_out, int out_size, void* d_ws, size_t ws_size,
                              hipStream_t stream) {
    const float* x    = (const float*)d_in[0];
    const float* ccs  = (const float*)d_in[1];
    const float* beta = (const float*)d_in[2];
    float* out = (float*)d_out;

    unsigned short* ccs_t = (unsigned short*)d_ws;                              // 128*288 bf16
    float* c_sq = (float*)((char*)d_ws + 128 * KD * sizeof(unsigned short));    // 128 f32

    hipMemsetAsync(c_sq, 0, NF * sizeof(float), stream);
    rbf_prologue<<<144, 256, 0, stream>>>(ccs, ccs_t, c_sq);
    rbf_main<<<dim3(55, 32), 256, 0, stream>>>(x, ccs_t, c_sq, beta, out);
}

// Round 4
// 269.432 us; speedup vs baseline: 1.0667x; 1.0667x over previous
//
#include <hip/hip_runtime.h>

// RBFolution: out[b,y,x,f] = exp(-beta[f] * (||patch||^2 - 2 patch.ccs[:,f] + ||ccs[:,f]||^2))
// x: [32,112,112,32] f32, ccs: [288,128] f32, beta: [128] f32, out: [32,110,110,128] f32
//
// bf16 MFMA implicit GEMM; p_sq/c_sq fp32-exact (only cross term bf16, err ~1e-5).
// R4: 4 output rows/block (fetch 2x->1.5x), XP=32 (pad removed -- access geometry is
// bank-uniform without it; 48 KB LDS -> 3 blocks/CU), c_sq folded into prologue
// (no memset dispatch).

typedef __attribute__((ext_vector_type(8))) short bf16x8;
typedef __attribute__((ext_vector_type(4))) float f32x4;

#define HH 112
#define WW 112
#define CC 32
#define HO 110
#define WO 110
#define NF 128
#define KD 288
#define RPX 114        // pixels per staged row in LDS (reads reach px 113)
#define XP 32          // bf16 elems per pixel (64 B): b128 frag reads spread uniformly over banks

__device__ __forceinline__ unsigned short f32_to_bf16(float f) {
    unsigned u = __float_as_uint(f);
    unsigned r = u + 0x7FFFu + ((u >> 16) & 1u);   // round-to-nearest-even
    return (unsigned short)(r >> 16);
}

// --- Prologue: ccs [288][128] f32 -> ccs_t [128][288] bf16 (all blocks);
//     block 0 threads 0..127 also compute c_sq[f] = sum_d ccs[d][f]^2 (coalesced column walk).
__global__ __launch_bounds__(256) void rbf_prologue(const float* __restrict__ ccs,
                                                    unsigned short* __restrict__ ccs_t,
                                                    float* __restrict__ c_sq) {
    int idx = blockIdx.x * 256 + threadIdx.x;     // 0..36863, coalesced read
    int d = idx >> 7;
    int f = idx & 127;
    ccs_t[f * KD + d] = f32_to_bf16(ccs[idx]);
    if (blockIdx.x == 0 && threadIdx.x < 128) {
        const int fc = threadIdx.x;
        float s = 0.f;
        #pragma unroll 8
        for (int dd = 0; dd < KD; ++dd) {
            float v = ccs[dd * NF + fc];
            s += v * v;
        }
        c_sq[fc] = s;
    }
}

// --- Main: one block per (4-row strip, b). 4 output rows, 6 staged input rows.
__global__ __launch_bounds__(256) void rbf_main(const float* __restrict__ x,
                                                const unsigned short* __restrict__ ccs_t,
                                                const float* __restrict__ c_sq,
                                                const float* __restrict__ beta,
                                                float* __restrict__ out) {
    __shared__ unsigned short xs[6 * RPX * XP];    // 43776 B
    __shared__ float colsum[676];                   // 6 rows x 112 cols (stride 112) + overrun pad
    __shared__ float p_sq[4 * 112];

    const int t = threadIdx.x;
    const int y0 = blockIdx.x * 4;  // 0,4,...,108
    const int b = blockIdx.y;       // 0..31
    const int rows = (HO - y0 < 4) ? (HO - y0) : 4;   // 4, or 2 for the tail strip

    // Stage x[y0..y0+5][0..111][0..31] -> LDS bf16; colsum from fp32 (exact p_sq).
    // 5376 float4 units = 21 * 256 exactly (no tail). Row index clamped to 111
    // (clamped rows feed only masked outputs).
    #pragma unroll
    for (int p = 0; p < 21; ++p) {
        int idx = t + p * 256;
        int q = idx & 7;              // channel quarter (4 floats)
        int ic = idx >> 3;            // 0..671 = i*112 + col
        int col = ic % 112;
        int i = ic / 112;
        int yg = y0 + i; if (yg > HH - 1) yg = HH - 1;
        const float4 v = *(const float4*)(x + ((size_t)(b * HH + yg) * WW + col) * CC + q * 4);
        unsigned short h0 = f32_to_bf16(v.x), h1 = f32_to_bf16(v.y);
        unsigned short h2 = f32_to_bf16(v.z), h3 = f32_to_bf16(v.w);
        uint2 pk;
        pk.x = (unsigned)h0 | ((unsigned)h1 << 16);
        pk.y = (unsigned)h2 | ((unsigned)h3 << 16);
        *(uint2*)(&xs[(i * RPX + col) * XP + q * 4]) = pk;   // 8B, contiguous 512B per wave
        float part = v.x * v.x + v.y * v.y + v.z * v.z + v.w * v.w;
        part += __shfl_xor(part, 1);
        part += __shfl_xor(part, 2);
        part += __shfl_xor(part, 4);
        if (q == 0) colsum[ic] = part;   // stride 112
    }
    __syncthreads();

    #pragma unroll
    for (int pp = 0; pp < 2; ++pp) {
        int idx = t + pp * 256;
        if (idx < 448) {
            int r = idx / 112;
            int c = idx - r * 112;
            float s = 0.f;
            #pragma unroll
            for (int i = 0; i < 3; ++i)
                #pragma unroll
                for (int j = 0; j < 3; ++j)
                    s += colsum[(r + i) * 112 + c + j];   // c>=110 reads pad garbage -> masked px only
            p_sq[idx] = s;
        }
    }
    __syncthreads();

    const int lane  = t & 63;
    const int wave  = t >> 6;            // 4 waves x 32 filters
    const int laneM = lane & 15;
    const int quad  = lane >> 4;

    // A = ccs (M = filters): lane's filter-in-tile = laneM
    const unsigned short* ap0 = ccs_t + (size_t)(wave * 32 + laneM) * KD + quad * 8;
    const unsigned short* ap1 = ap0 + 16 * KD;

    // per-lane 4 consecutive filters (rows of D): f = wave*32 + ft*16 + quad*4 + e
    const int fb = wave * 32 + quad * 4;
    const float4 cs0 = *(const float4*)(c_sq + fb);
    const float4 cs1 = *(const float4*)(c_sq + fb + 16);
    const float4 bt0 = *(const float4*)(beta + fb);
    const float4 bt1 = *(const float4*)(beta + fb + 16);

    for (int r = 0; r < rows; ++r) {
        f32x4 acc[7][2];
        #pragma unroll
        for (int mi = 0; mi < 7; ++mi) {
            acc[mi][0] = (f32x4){0.f, 0.f, 0.f, 0.f};
            acc[mi][1] = (f32x4){0.f, 0.f, 0.f, 0.f};
        }

        #pragma unroll
        for (int kb = 0; kb < 9; ++kb) {     // one k-block per tap (ki,kj), K=32 channels
            const int ki = kb / 3, kj = kb % 3;
            bf16x8 a0 = *(const bf16x8*)(ap0 + kb * 32);
            bf16x8 a1 = *(const bf16x8*)(ap1 + kb * 32);
            #pragma unroll
            for (int mi = 0; mi < 7; ++mi) {
                // B[k = quad*8+j][n = laneM]: pixel px = mi*16+laneM+kj, staged row r+ki
                const bf16x8 bf = *(const bf16x8*)(&xs[((r + ki) * RPX + mi * 16 + laneM + kj) * XP + quad * 8]);
                acc[mi][0] = __builtin_amdgcn_mfma_f32_16x16x32_bf16(a0, bf, acc[mi][0], 0, 0, 0);
                acc[mi][1] = __builtin_amdgcn_mfma_f32_16x16x32_bf16(a1, bf, acc[mi][1], 0, 0, 0);
            }
        }

        // Epilogue: D[row = filter (quad*4+e)][col = pixel (laneM)] -> float4 stores along filters
        float* orow = out + (size_t)((b * HO + y0 + r) * WO) * NF;
        #pragma unroll
        for (int mi = 0; mi < 7; ++mi) {
            const int px = mi * 16 + laneM;
            const float ps = p_sq[r * 112 + px];
            float* op = orow + (size_t)px * NF + fb;
            #pragma unroll
            for (int ft = 0; ft < 2; ++ft) {
                const float4 cs = ft ? cs1 : cs0;
                const float4 bt = ft ? bt1 : bt0;
                float4 o;
                o.x = __expf(-bt.x * (ps - 2.f * acc[mi][ft][0] + cs.x));
                o.y = __expf(-bt.y * (ps - 2.f * acc[mi][ft][1] + cs.y));
                o.z = __expf(-bt.z * (ps - 2.f * acc[mi][ft][2] + cs.z));
                o.w = __expf(-bt.w * (ps - 2.f * acc[mi][ft][3] + cs.w));
                if (px < WO)
                    *(float4*)(op + ft * 16) = o;
            }
        }
    }
}

extern "C" void kernel_launch(void* const* d_in, const int* in_sizes, int n_in,
                              void* d_out, int out_size, void* d_ws, size_t ws_size,
                              hipStream_t stream) {
    const float* x    = (const float*)d_in[0];
    const float* ccs  = (const float*)d_in[1];
    const float* beta = (const float*)d_in[2];
    float* out = (float*)d_out;

    unsigned short* ccs_t = (unsigned short*)d_ws;                              // 128*288 bf16
    float* c_sq = (float*)((char*)d_ws + 128 * KD * sizeof(unsigned short));    // 128 f32

    rbf_prologue<<<144, 256, 0, stream>>>(ccs, ccs_t, c_sq);
    rbf_main<<<dim3(28, 32), 256, 0, stream>>>(x, ccs_t, c_sq, beta, out);
}